// Round 8
// baseline (203.530 us; speedup 1.0000x reference)
//
#include <hip/hip_runtime.h>
#include <hip/hip_bf16.h>

using bf16 = __hip_bfloat16;
typedef __bf16 bf16x8_t __attribute__((ext_vector_type(8)));
typedef float f32x4_t __attribute__((ext_vector_type(4)));

// ---------------------------------------------------------------- helpers
__device__ __forceinline__ void gl16(bf16* l, const bf16* g) {
  // async global->LDS, 16B per lane; LDS dest must be linear (base + lane*16)
  __builtin_amdgcn_global_load_lds(
      (const __attribute__((address_space(1))) unsigned int*)g,
      (__attribute__((address_space(3))) unsigned int*)l, 16, 0, 0);
}

#define BARRIER() do { asm volatile("" ::: "memory"); __builtin_amdgcn_s_barrier(); asm volatile("" ::: "memory"); } while (0)
#define WAITVM(N) asm volatile("s_waitcnt vmcnt(" #N ")" ::: "memory")
#define SCHED0() __builtin_amdgcn_sched_barrier(0)

// ---------------------------------------------------------------- fused prep: cvt x + transpose both W
__global__ __launch_bounds__(256) void prep_fused(const float* __restrict__ x,
                                                  const float* __restrict__ Wqkv,
                                                  const float* __restrict__ Wout,
                                                  bf16* __restrict__ xb,
                                                  bf16* __restrict__ w1t,
                                                  bf16* __restrict__ w2t) {
  __shared__ float t[32][33];
  const int bid = blockIdx.x;
  if (bid < 16384) {  // cvt: 4 f32 per thread
    int i = bid * 256 + threadIdx.x;
    float4 v = ((const float4*)x)[i];
    union { ushort4 u; bf16 b[4]; } o;
    o.b[0] = __float2bfloat16(v.x);
    o.b[1] = __float2bfloat16(v.y);
    o.b[2] = __float2bfloat16(v.z);
    o.b[3] = __float2bfloat16(v.w);
    ((ushort4*)xb)[i] = o.u;
    return;
  }
  const float* in; bf16* out; int R, C, gx, gy;
  if (bid < 16384 + 3072) {
    int idx = bid - 16384; in = Wqkv; out = w1t; R = 1024; C = 3072;
    gx = idx % 96; gy = idx / 96;
  } else {
    int idx = bid - 16384 - 3072; in = Wout; out = w2t; R = 1024; C = 1024;
    gx = idx & 31; gy = idx >> 5;
  }
  int bx = gx * 32, by = gy * 32;
  int tx = threadIdx.x & 31, ty = threadIdx.x >> 5;  // ty 0..7
#pragma unroll
  for (int r = 0; r < 32; r += 8)
    t[ty + r][tx] = in[(size_t)(by + ty + r) * C + bx + tx];
  __syncthreads();
#pragma unroll
  for (int r = 0; r < 32; r += 8)
    out[(size_t)(bx + ty + r) * R + by + tx] = __float2bfloat16(t[tx][ty + r]);
}

// ---------------------------------------------------------------- 256x256 bf16 GEMM, BK=32, 4-deep pipeline
// C[M=16384, N=NWGX*256] = A @ Bt^T + bias. K=1024 -> 32 K-steps/tile, grid 256x512thr.
// LDS = 4 circular bufs x 32KB (buf = kstep & 3): A[256][32] at +0, B[256][32] at +8192 elems.
// During step g we stage step g+3 (A at ph1, B at ph2): prefetch distance 3 steps covers
// HBM latency. Steady outstanding before ph4 wait = 12 loads; vmcnt(8) drains exactly g+1.
// Fragments af1(A,MH0) af2(A,MH1) b0(B,NH0) b1(B,NH1), each LDS-read once/step, one phase
// ahead of first use. Swizzle: 16B-chunk ^= row&3 (bijective over 16rows x 4chunks ->
// conflict-free b128); inverse applied on staging source (LDS dest linear).
// Hazard audit: every stage-write into buf[(g+3)&3] (= step g-1's buf) issues >=2 barriers
// after the last ds_read of step g-1's data completed (reads forced complete by the MFMA
// consuming them one phase later, pre-barrier in program order).

__device__ __forceinline__ void readA(const bf16* buf, int MH, int wr, int lr, int lg,
                                      bf16x8_t (&af)[4]) {
#pragma unroll
  for (int mi = 0; mi < 4; ++mi) {
    int R = wr * 128 + MH * 64 + mi * 16 + lr;
    af[mi] = *(const bf16x8_t*)(buf + R * 32 + ((lg ^ (R & 3)) << 3));
  }
}
__device__ __forceinline__ void readB(const bf16* buf, int NH, int wc, int lr, int lg,
                                      bf16x8_t (&bfr)[2]) {
  const bf16* bb = buf + 8192;
#pragma unroll
  for (int ni = 0; ni < 2; ++ni) {
    int R = wc * 64 + NH * 32 + ni * 16 + lr;
    bfr[ni] = *(const bf16x8_t*)(bb + R * 32 + ((lg ^ (R & 3)) << 3));
  }
}

template <int MH, int NH>
__device__ __forceinline__ void mfma8(bf16x8_t (&af)[4], bf16x8_t (&bfr)[2],
                                      f32x4_t (&acc)[8][4]) {
  __builtin_amdgcn_s_setprio(1);
#pragma unroll
  for (int mi = 0; mi < 4; ++mi)
#pragma unroll
    for (int ni = 0; ni < 2; ++ni)
      acc[MH * 4 + mi][NH * 2 + ni] = __builtin_amdgcn_mfma_f32_16x16x32_bf16(
          af[mi], bfr[ni], acc[MH * 4 + mi][NH * 2 + ni], 0, 0, 0);
  __builtin_amdgcn_s_setprio(0);
}

template <int OUT_BF16, int NWGX>
__global__ __launch_bounds__(512, 2) void gemm256p(const bf16* __restrict__ A,
                                                   const bf16* __restrict__ Bt,
                                                   const float* __restrict__ bias,
                                                   void* __restrict__ Cv) {
  constexpr int K = 1024;
  constexpr int N = NWGX * 256;
  constexpr int TT = NWGX / 4;     // output tiles per block (grid fixed at 256)
  constexpr int G = TT * 32;       // flattened K-steps (BK=32)
  constexpr int CPX = NWGX * 8;    // tiles per XCD chunk

  __shared__ __align__(16) bf16 lds[65536];  // 4 bufs x 16384 elems (32KB each)
  const int tid = threadIdx.x;
  const int bx = blockIdx.x;

  const int wid = tid >> 6, lane = tid & 63;
  const int wr = wid >> 2, wc = wid & 3;
  const int lr = lane & 15, lg = lane >> 4;

  const int srow = tid >> 2;                              // 0..127
  const int colg = (((tid & 3) ^ (srow & 3)) << 3);       // pre-swizzled 16B chunk (elems)

  auto tileMN = [&](int tt, int& m0, int& n0) {
    int orig = bx + (tt << 8);
    int swz = (orig & 7) * CPX + (orig >> 3);
    m0 = (swz / NWGX) * 256;
    n0 = (swz % NWGX) * 256;
  };

  auto stageA = [&](int g) {  // stage A[256][32] of K-step g into buf g&3 (2 loads)
    if (g >= G) return;
    int m0, n0; tileMN(g >> 5, m0, n0);
    const bf16* g0 = A + (size_t)(m0 + srow) * K + (g & 31) * 32 + colg;
    bf16* l = lds + (g & 3) * 16384 + tid * 8;
    gl16(l, g0); gl16(l + 4096, g0 + (size_t)128 * K);
  };
  auto stageB = [&](int g) {  // stage B[256][32] (2 loads)
    if (g >= G) return;
    int m0, n0; tileMN(g >> 5, m0, n0);
    const bf16* g0 = Bt + (size_t)(n0 + srow) * K + (g & 31) * 32 + colg;
    bf16* l = lds + (g & 3) * 16384 + 8192 + tid * 8;
    gl16(l, g0); gl16(l + 4096, g0 + (size_t)128 * K);
  };

  f32x4_t acc[8][4] = {};
  bf16x8_t af1[4], af2[4], b0[2], b1[2];

  // prologue: stage steps 0,1,2 (12 loads); drain step 0; first reads
  stageA(0); stageB(0); stageA(1); stageB(1); stageA(2); stageB(2);
  WAITVM(8);
  BARRIER();
  readA(lds, 0, wr, lr, lg, af1);   // A(0) MH=0
  readB(lds, 0, wc, lr, lg, b0);    // B(0) NH=0

  for (int g = 0; g < G; ++g) {
    const bf16* cb = lds + (g & 3) * 16384;
    const bf16* nb = lds + ((g + 1) & 3) * 16384;

    // phase 1: Q(0,0) = af1 x b0 ; read b1(g); stage A(g+3)
    stageA(g + 3);
    BARRIER();
    readB(cb, 1, wc, lr, lg, b1);
    SCHED0();
    mfma8<0, 0>(af1, b0, acc);

    // phase 2: Q(0,1) = af1 x b1 ; read af2(g); stage B(g+3)
    stageB(g + 3);
    BARRIER();
    readA(cb, 1, wr, lr, lg, af2);
    SCHED0();
    mfma8<0, 1>(af1, b1, acc);

    // phase 3: Q(1,0) = af2 x b0
    BARRIER();
    mfma8<1, 0>(af2, b0, acc);

    // phase 4: Q(1,1) = af2 x b1 ; wait step g+1 resident; read af1,b0 (g+1)
    if (g + 3 < G)       { WAITVM(8); }
    else if (g + 3 == G) { WAITVM(4); }
    else if (g + 2 == G) { WAITVM(0); }
    BARRIER();
    if (g < G - 1) {
      readA(nb, 0, wr, lr, lg, af1);
      readB(nb, 0, wc, lr, lg, b0);
      SCHED0();
    }
    mfma8<1, 1>(af2, b1, acc);

    if ((g & 31) == 31) {
      BARRIER();  // keep dump stores out of the last phase's read window
      // dump finished tile; n innermost so each 64B C-line completes back-to-back
      int m0, n0; tileMN(g >> 5, m0, n0);
      float bv[4];
#pragma unroll
      for (int n = 0; n < 4; ++n) bv[n] = bias[n0 + wc * 64 + n * 16 + lr];
#pragma unroll
      for (int m = 0; m < 8; ++m) {
        int row = m0 + wr * 128 + m * 16 + lg * 4;
#pragma unroll
        for (int j = 0; j < 4; ++j) {
#pragma unroll
          for (int n = 0; n < 4; ++n) {
            int col = n0 + wc * 64 + n * 16 + lr;
            float v = acc[m][n][j] + bv[n];
            if (OUT_BF16)
              ((bf16*)Cv)[(size_t)(row + j) * N + col] = __float2bfloat16(v);
            else
              ((float*)Cv)[(size_t)(row + j) * N + col] = v;
            acc[m][n][j] = 0.f;
          }
        }
      }
    }
  }
}

// ---------------------------------------------------------------- per-token head-mixing attention (MFMA)
// qkv[t][0:1024]=q, [1024:2048]=k, [2048:3072]=v ; head layout idx = h*64+d
// logits[qh][kh] = 0.125 * dot(q[qh], k[kh]); softmax over kh; out[qh][d] = sum_kh p*v[kh][d]
#define PSTR 48
__global__ __launch_bounds__(256) void attn_tok(const bf16* __restrict__ qkv,
                                                bf16* __restrict__ out) {
  __shared__ __align__(16) bf16 vs[4][1024];
  __shared__ __align__(16) bf16 ps[4][16 * PSTR];
  const int w = threadIdx.x >> 6, l = threadIdx.x & 63;
  const int t = blockIdx.x * 4 + w;
  const int lr = l & 15, lg = l >> 4;
  const bf16* base = qkv + (size_t)t * 3072;

  bf16x8_t v0 = *(const bf16x8_t*)(base + 2048 + l * 16);
  bf16x8_t v1 = *(const bf16x8_t*)(base + 2048 + l * 16 + 8);
  *(bf16x8_t*)(&vs[w][l * 16]) = v0;
  *(bf16x8_t*)(&vs[w][l * 16 + 8]) = v1;

  *(unsigned long long*)(&ps[w][(l >> 2) * PSTR + 16 + (l & 3) * 4]) = 0ULL;

  const bf16* qp = base + lr * 64 + lg * 8;
  const bf16* kp = base + 1024 + lr * 64 + lg * 8;
  bf16x8_t qa0 = *(const bf16x8_t*)qp;
  bf16x8_t ka0 = *(const bf16x8_t*)kp;
  bf16x8_t qa1 = *(const bf16x8_t*)(qp + 32);
  bf16x8_t ka1 = *(const bf16x8_t*)(kp + 32);
  f32x4_t s = {};
  s = __builtin_amdgcn_mfma_f32_16x16x32_bf16(qa0, ka0, s, 0, 0, 0);
  s = __builtin_amdgcn_mfma_f32_16x16x32_bf16(qa1, ka1, s, 0, 0, 0);

#pragma unroll
  for (int j = 0; j < 4; ++j) {
    float x = s[j] * 0.125f;
    float mx = x;
#pragma unroll
    for (int off = 8; off; off >>= 1) mx = fmaxf(mx, __shfl_xor(mx, off, 16));
    float e = __expf(x - mx);
    float sum = e;
#pragma unroll
    for (int off = 8; off; off >>= 1) sum += __shfl_xor(sum, off, 16);
    ps[w][(lg * 4 + j) * PSTR + lr] = __float2bfloat16(e / sum);
  }

  bf16x8_t pf = *(const bf16x8_t*)(&ps[w][lr * PSTR + lg * 8]);
  bf16x8_t vf[4] = {};
  if (l < 32) {
#pragma unroll
    for (int c = 0; c < 4; ++c)
#pragma unroll
      for (int j = 0; j < 8; ++j)
        vf[c][j] = (__bf16)vs[w][(lg * 8 + j) * 64 + c * 16 + lr];
  }
  f32x4_t o[4] = {};
#pragma unroll
  for (int c = 0; c < 4; ++c)
    o[c] = __builtin_amdgcn_mfma_f32_16x16x32_bf16(pf, vf[c], o[c], 0, 0, 0);

  bf16* ob = out + (size_t)t * 1024;
#pragma unroll
  for (int c = 0; c < 4; ++c)
#pragma unroll
    for (int j = 0; j < 4; ++j)
      ob[(lg * 4 + j) * 64 + c * 16 + lr] = __float2bfloat16(o[c][j]);
}

// ---------------------------------------------------------------- launch
extern "C" void kernel_launch(void* const* d_in, const int* in_sizes, int n_in,
                              void* d_out, int out_size, void* d_ws, size_t ws_size,
                              hipStream_t stream) {
  const float* x    = (const float*)d_in[0];  // [16384,1024]
  const float* Wqkv = (const float*)d_in[1];  // [1024,3072]
  const float* bqkv = (const float*)d_in[2];  // [3072]
  const float* Wout = (const float*)d_in[3];  // [1024,1024]
  const float* bout = (const float*)d_in[4];  // [1024]
  float* y = (float*)d_out;                   // [16384,1024]

  const int T = 16384, HD = 1024, N1 = 3072;

  char* ws = (char*)d_ws;
  size_t off = 0;
  bf16* xb  = (bf16*)(ws + off); off += (size_t)T * HD * 2;
  bf16* w1t = (bf16*)(ws + off); off += (size_t)N1 * HD * 2;
  bf16* w2t = (bf16*)(ws + off); off += (size_t)HD * HD * 2;
  bf16* qkv = (bf16*)(ws + off); off += (size_t)T * N1 * 2;
  if (ws_size < off) return;
  bf16* ao = xb;  // xb dead after GEMM1; reuse as attention output

  prep_fused<<<16384 + 3072 + 1024, 256, 0, stream>>>(x, Wqkv, Wout, xb, w1t, w2t);
  gemm256p<1, 12><<<256, 512, 0, stream>>>(xb, w1t, bqkv, qkv);
  attn_tok<<<T / 4, 256, 0, stream>>>(qkv, ao);
  gemm256p<0, 4><<<256, 512, 0, stream>>>(ao, w2t, bout, y);
}

// Round 9
// 199.461 us; speedup vs baseline: 1.0204x; 1.0204x over previous
//
#include <hip/hip_runtime.h>
#include <hip/hip_bf16.h>

using bf16 = __hip_bfloat16;
typedef __bf16 bf16x8_t __attribute__((ext_vector_type(8)));
typedef float f32x4_t __attribute__((ext_vector_type(4)));

// ---------------------------------------------------------------- helpers
__device__ __forceinline__ void gl16(bf16* l, const bf16* g) {
  // async global->LDS, 16B per lane; LDS dest must be linear (base + lane*16)
  __builtin_amdgcn_global_load_lds(
      (const __attribute__((address_space(1))) unsigned int*)g,
      (__attribute__((address_space(3))) unsigned int*)l, 16, 0, 0);
}

#define BARRIER() do { asm volatile("" ::: "memory"); __builtin_amdgcn_s_barrier(); asm volatile("" ::: "memory"); } while (0)
#define WAITVM(N) asm volatile("s_waitcnt vmcnt(" #N ")" ::: "memory")
#define LGKM0() do { asm volatile("s_waitcnt lgkmcnt(0)" ::: "memory"); __builtin_amdgcn_sched_barrier(0); } while (0)

// ---------------------------------------------------------------- fused prep: cvt x + transpose both W
__global__ __launch_bounds__(256) void prep_fused(const float* __restrict__ x,
                                                  const float* __restrict__ Wqkv,
                                                  const float* __restrict__ Wout,
                                                  bf16* __restrict__ xb,
                                                  bf16* __restrict__ w1t,
                                                  bf16* __restrict__ w2t) {
  __shared__ float t[32][33];
  const int bid = blockIdx.x;
  if (bid < 16384) {  // cvt: 4 f32 per thread
    int i = bid * 256 + threadIdx.x;
    float4 v = ((const float4*)x)[i];
    union { ushort4 u; bf16 b[4]; } o;
    o.b[0] = __float2bfloat16(v.x);
    o.b[1] = __float2bfloat16(v.y);
    o.b[2] = __float2bfloat16(v.z);
    o.b[3] = __float2bfloat16(v.w);
    ((ushort4*)xb)[i] = o.u;
    return;
  }
  const float* in; bf16* out; int R, C, gx, gy;
  if (bid < 16384 + 3072) {
    int idx = bid - 16384; in = Wqkv; out = w1t; R = 1024; C = 3072;
    gx = idx % 96; gy = idx / 96;
  } else {
    int idx = bid - 16384 - 3072; in = Wout; out = w2t; R = 1024; C = 1024;
    gx = idx & 31; gy = idx >> 5;
  }
  int bx = gx * 32, by = gy * 32;
  int tx = threadIdx.x & 31, ty = threadIdx.x >> 5;  // ty 0..7
#pragma unroll
  for (int r = 0; r < 32; r += 8)
    t[ty + r][tx] = in[(size_t)(by + ty + r) * C + bx + tx];
  __syncthreads();
#pragma unroll
  for (int r = 0; r < 32; r += 8)
    out[(size_t)(bx + ty + r) * R + by + tx] = __float2bfloat16(t[tx][ty + r]);
}

// ---------------------------------------------------------------- 256x256 bf16 GEMM, m201-style 4-phase schedule, persistent
// C[M=16384, N=NWGX*256] = A @ Bt^T + bias. K=1024 (16 K-steps/tile of BK=64), grid 256x512thr.
// LDS: 2 bufs x {Ah0,Ah1,Bh0,Bh1} halves of [128 rows][64 cols] bf16 (16KB each).
// Per K-step g, 4 phases (C-quadrants). Phase = { ds_read CURRENT subtile; stage 1 half;
// BARRIER; lgkmcnt(0); MFMA x16; BARRIER }. Stage slots: ph1:B1(g+1) ph2:A0(g+2)
// ph3:B0(g+2) ph4:A1(g+2)+vmcnt(6). vmcnt(6) leaves exactly {A0,B0,A1}(g+2) in flight and
// makes step g+1 fully resident. Tail: ph4(G-2) uses vmcnt(0) (its t+2-stages are no-ops,
// vmcnt(6) would strand B1(G-1)). WAR: every stage targets a region whose reads completed
// at a post-barrier lgkmcnt(0) >=1 phase earlier.

__device__ __forceinline__ void readA(const bf16* lb, int half, int wr, int lr, int lg, int exr,
                                      bf16x8_t (&af)[4][2]) {
  const bf16* ab = lb + half * 8192;
#pragma unroll
  for (int mi = 0; mi < 4; ++mi) {
    int R = wr * 64 + mi * 16 + lr;
    af[mi][0] = *(const bf16x8_t*)(ab + R * 64 + ((lg * 8) ^ exr));
    af[mi][1] = *(const bf16x8_t*)(ab + R * 64 + ((32 + lg * 8) ^ exr));
  }
}
__device__ __forceinline__ void readB(const bf16* lb, int half, int wc, int lr, int lg, int exr,
                                      bf16x8_t (&bfr)[2][2]) {
  const bf16* bb = lb + (2 + half) * 8192;
#pragma unroll
  for (int ni = 0; ni < 2; ++ni) {
    int R = wc * 32 + ni * 16 + lr;
    bfr[ni][0] = *(const bf16x8_t*)(bb + R * 64 + ((lg * 8) ^ exr));
    bfr[ni][1] = *(const bf16x8_t*)(bb + R * 64 + ((32 + lg * 8) ^ exr));
  }
}

template <int MH, int NH>
__device__ __forceinline__ void mfma16(bf16x8_t (&af)[4][2], bf16x8_t (&bfr)[2][2],
                                       f32x4_t (&acc)[8][4]) {
  __builtin_amdgcn_s_setprio(1);
#pragma unroll
  for (int mi = 0; mi < 4; ++mi)
#pragma unroll
    for (int ni = 0; ni < 2; ++ni) {
      f32x4_t& a = acc[MH * 4 + mi][NH * 2 + ni];
      a = __builtin_amdgcn_mfma_f32_16x16x32_bf16(af[mi][0], bfr[ni][0], a, 0, 0, 0);
      a = __builtin_amdgcn_mfma_f32_16x16x32_bf16(af[mi][1], bfr[ni][1], a, 0, 0, 0);
    }
  __builtin_amdgcn_s_setprio(0);
}

template <int OUT_BF16, int NWGX>
__global__ __launch_bounds__(512, 2) void gemm256p(const bf16* __restrict__ A,
                                                   const bf16* __restrict__ Bt,
                                                   const float* __restrict__ bias,
                                                   void* __restrict__ Cv) {
  constexpr int K = 1024;
  constexpr int N = NWGX * 256;
  constexpr int TT = NWGX / 4;     // output tiles per block (grid fixed at 256)
  constexpr int G = TT * 16;       // flattened K-steps (BK=64)
  constexpr int CPX = NWGX * 8;    // tiles per XCD chunk

  __shared__ __align__(16) bf16 lds[65536];  // 128 KiB: 2 bufs x 4 halves x 8192 elems
  const int tid = threadIdx.x;
  const int bx = blockIdx.x;

  const int wid = tid >> 6, lane = tid & 63;
  const int wr = wid >> 2, wc = wid & 3;
  const int lr = lane & 15, lg = lane >> 4;
  const int exr = (lr & 7) << 3;

  const int srow = tid >> 3;
  const int colg = ((((tid & 7) * 16) ^ ((srow & 7) << 4)) >> 1);
  const int browc0 = (srow >> 5) * 64 + (srow & 31);

  auto tileMN = [&](int tt, int& m0, int& n0) {
    int orig = bx + (tt << 8);
    int swz = (orig & 7) * CPX + (orig >> 3);
    m0 = (swz / NWGX) * 256;
    n0 = (swz % NWGX) * 256;
  };

  auto stageA = [&](int g, int h) {
    if (g >= G) return;
    int m0, n0; tileMN(g >> 4, m0, n0);
    const bf16* g0 = A + (size_t)(m0 + h * 64 + srow) * K + (g & 15) * 64 + colg;
    bf16* l = lds + (g & 1) * 32768 + h * 8192 + tid * 8;
    gl16(l, g0); gl16(l + 4096, g0 + (size_t)128 * K);
  };
  auto stageB = [&](int g, int h) {
    if (g >= G) return;
    int m0, n0; tileMN(g >> 4, m0, n0);
    const bf16* g0 = Bt + (size_t)(n0 + browc0 + h * 32) * K + (g & 15) * 64 + colg;
    bf16* l = lds + (g & 1) * 32768 + (2 + h) * 8192 + tid * 8;
    gl16(l, g0); gl16(l + 4096, g0 + (size_t)128 * K);
  };

  f32x4_t acc[8][4] = {};
  bf16x8_t a1[4][2], a2[4][2], b0[2][2], b1[2][2];

  // prologue: step 0 fully + {A0,B0,A1}(1) in flight; vmcnt(6) = steady post-ph4 state
  stageA(0, 0); stageB(0, 0); stageA(0, 1); stageB(0, 1);
  stageA(1, 0); stageB(1, 0); stageA(1, 1);
  WAITVM(6);
  BARRIER();

  for (int g = 0; g < G; ++g) {
    const bf16* cb = lds + (g & 1) * 32768;

    // phase 1: Q(0,0) = A0 x B0 (12 ds_reads) ; stage B1(g+1)
    readA(cb, 0, wr, lr, lg, exr, a1);
    readB(cb, 0, wc, lr, lg, exr, b0);
    stageB(g + 1, 1);
    BARRIER();
    LGKM0();
    mfma16<0, 0>(a1, b0, acc);
    BARRIER();

    // phase 2: Q(0,1) = A0 x B1 (4 ds_reads) ; stage A0(g+2)
    readB(cb, 1, wc, lr, lg, exr, b1);
    stageA(g + 2, 0);
    BARRIER();
    LGKM0();
    mfma16<0, 1>(a1, b1, acc);
    BARRIER();

    // phase 3: Q(1,0) = A1 x B0 (8 ds_reads) ; stage B0(g+2)
    readA(cb, 1, wr, lr, lg, exr, a2);
    stageB(g + 2, 0);
    BARRIER();
    LGKM0();
    mfma16<1, 0>(a2, b0, acc);
    BARRIER();

    // phase 4: Q(1,1) = A1 x B1 (no reads) ; stage A1(g+2) ; counted wait
    stageA(g + 2, 1);
    if (g + 2 < G)       { WAITVM(6); }
    else if (g + 2 == G) { WAITVM(0); }  // tail: t+2-stages were no-ops; drain B1(G-1)
    BARRIER();
    mfma16<1, 1>(a2, b1, acc);
    BARRIER();

    if ((g & 15) == 15) {
      // dump finished tile; n innermost so each 64B C-line completes back-to-back
      int m0, n0; tileMN(g >> 4, m0, n0);
      float bv[4];
#pragma unroll
      for (int n = 0; n < 4; ++n) bv[n] = bias[n0 + wc * 64 + n * 16 + lr];
#pragma unroll
      for (int m = 0; m < 8; ++m) {
        int row = m0 + wr * 128 + m * 16 + lg * 4;
#pragma unroll
        for (int j = 0; j < 4; ++j) {
#pragma unroll
          for (int n = 0; n < 4; ++n) {
            int col = n0 + wc * 64 + n * 16 + lr;
            float v = acc[m][n][j] + bv[n];
            if (OUT_BF16)
              ((bf16*)Cv)[(size_t)(row + j) * N + col] = __float2bfloat16(v);
            else
              ((float*)Cv)[(size_t)(row + j) * N + col] = v;
            acc[m][n][j] = 0.f;
          }
        }
      }
    }
  }
}

// ---------------------------------------------------------------- per-token head-mixing attention (MFMA)
// qkv[t][0:1024]=q, [1024:2048]=k, [2048:3072]=v ; head layout idx = h*64+d
// logits[qh][kh] = 0.125 * dot(q[qh], k[kh]); softmax over kh; out[qh][d] = sum_kh p*v[kh][d]
#define PSTR 48
__global__ __launch_bounds__(256) void attn_tok(const bf16* __restrict__ qkv,
                                                bf16* __restrict__ out) {
  __shared__ __align__(16) bf16 vs[4][1024];
  __shared__ __align__(16) bf16 ps[4][16 * PSTR];
  const int w = threadIdx.x >> 6, l = threadIdx.x & 63;
  const int t = blockIdx.x * 4 + w;
  const int lr = l & 15, lg = l >> 4;
  const bf16* base = qkv + (size_t)t * 3072;

  bf16x8_t v0 = *(const bf16x8_t*)(base + 2048 + l * 16);
  bf16x8_t v1 = *(const bf16x8_t*)(base + 2048 + l * 16 + 8);
  *(bf16x8_t*)(&vs[w][l * 16]) = v0;
  *(bf16x8_t*)(&vs[w][l * 16 + 8]) = v1;

  *(unsigned long long*)(&ps[w][(l >> 2) * PSTR + 16 + (l & 3) * 4]) = 0ULL;

  const bf16* qp = base + lr * 64 + lg * 8;
  const bf16* kp = base + 1024 + lr * 64 + lg * 8;
  bf16x8_t qa0 = *(const bf16x8_t*)qp;
  bf16x8_t ka0 = *(const bf16x8_t*)kp;
  bf16x8_t qa1 = *(const bf16x8_t*)(qp + 32);
  bf16x8_t ka1 = *(const bf16x8_t*)(kp + 32);
  f32x4_t s = {};
  s = __builtin_amdgcn_mfma_f32_16x16x32_bf16(qa0, ka0, s, 0, 0, 0);
  s = __builtin_amdgcn_mfma_f32_16x16x32_bf16(qa1, ka1, s, 0, 0, 0);

#pragma unroll
  for (int j = 0; j < 4; ++j) {
    float x = s[j] * 0.125f;
    float mx = x;
#pragma unroll
    for (int off = 8; off; off >>= 1) mx = fmaxf(mx, __shfl_xor(mx, off, 16));
    float e = __expf(x - mx);
    float sum = e;
#pragma unroll
    for (int off = 8; off; off >>= 1) sum += __shfl_xor(sum, off, 16);
    ps[w][(lg * 4 + j) * PSTR + lr] = __float2bfloat16(e / sum);
  }

  bf16x8_t pf = *(const bf16x8_t*)(&ps[w][lr * PSTR + lg * 8]);
  bf16x8_t vf[4] = {};
  if (l < 32) {
#pragma unroll
    for (int c = 0; c < 4; ++c)
#pragma unroll
      for (int j = 0; j < 8; ++j)
        vf[c][j] = (__bf16)vs[w][(lg * 8 + j) * 64 + c * 16 + lr];
  }
  f32x4_t o[4] = {};
#pragma unroll
  for (int c = 0; c < 4; ++c)
    o[c] = __builtin_amdgcn_mfma_f32_16x16x32_bf16(pf, vf[c], o[c], 0, 0, 0);

  bf16* ob = out + (size_t)t * 1024;
#pragma unroll
  for (int c = 0; c < 4; ++c)
#pragma unroll
    for (int j = 0; j < 4; ++j)
      ob[(lg * 4 + j) * 64 + c * 16 + lr] = __float2bfloat16(o[c][j]);
}

// ---------------------------------------------------------------- launch
extern "C" void kernel_launch(void* const* d_in, const int* in_sizes, int n_in,
                              void* d_out, int out_size, void* d_ws, size_t ws_size,
                              hipStream_t stream) {
  const float* x    = (const float*)d_in[0];  // [16384,1024]
  const float* Wqkv = (const float*)d_in[1];  // [1024,3072]
  const float* bqkv = (const float*)d_in[2];  // [3072]
  const float* Wout = (const float*)d_in[3];  // [1024,1024]
  const float* bout = (const float*)d_in[4];  // [1024]
  float* y = (float*)d_out;                   // [16384,1024]

  const int T = 16384, HD = 1024, N1 = 3072;

  char* ws = (char*)d_ws;
  size_t off = 0;
  bf16* xb  = (bf16*)(ws + off); off += (size_t)T * HD * 2;
  bf16* w1t = (bf16*)(ws + off); off += (size_t)N1 * HD * 2;
  bf16* w2t = (bf16*)(ws + off); off += (size_t)HD * HD * 2;
  bf16* qkv = (bf16*)(ws + off); off += (size_t)T * N1 * 2;
  if (ws_size < off) return;
  bf16* ao = xb;  // xb dead after GEMM1; reuse as attention output

  prep_fused<<<16384 + 3072 + 1024, 256, 0, stream>>>(x, Wqkv, Wout, xb, w1t, w2t);
  gemm256p<1, 12><<<256, 512, 0, stream>>>(xb, w1t, bqkv, qkv);
  attn_tok<<<T / 4, 256, 0, stream>>>(qkv, ao);
  gemm256p<0, 4><<<256, 512, 0, stream>>>(ao, w2t, bout, y);
}